// Round 2
// baseline (273.879 us; speedup 1.0000x reference)
//
#include <hip/hip_runtime.h>

#define T_DEPTH 200000
#define V_DIM   130
#define H_DIM   512

// d_out offsets (fp32 elements): ot, Val, stg, rt, h_new, c_new
#define OT_OFF   0
#define VAL_OFF  512
#define STG_OFF  26000642
#define RT_OFF   26200643
#define HN_OFF   26200773
#define CN_OFF   26201797

// ws offsets (floats)
#define WS_G0     0
#define WS_H1     2048
#define WS_C1     2560
#define WS_G1     3072
#define WS_H2     5120
#define WS_C2     5632
#define WS_VTACC  6144
#define WS_OTACC  6274
#define WS_DTUT   6786
#define WS_VT     6788
#define WS_TOTAL  6918

static __device__ __forceinline__ float sigmoidf(float x) {
    return 1.0f / (1.0f + expf(-x));
}

// ---- big copy: prev_Val -> Val rows [0,T) (float4), prev_stg -> stg[0,T) (float2)
__global__ void k_bulk(const float4* __restrict__ val_in,
                       const float2* __restrict__ stg_in,
                       float* __restrict__ out) {
    const int NV4 = (T_DEPTH * V_DIM) / 4;   // 6,500,000
    const int NS2 = T_DEPTH / 2;             // 100,000
    const int NT  = NV4 + NS2;
    float4* __restrict__ val_out = reinterpret_cast<float4*>(out + VAL_OFF); // 16B aligned
    float2* __restrict__ stg_out = reinterpret_cast<float2*>(out + STG_OFF); // 8B aligned
    int stride = gridDim.x * blockDim.x;
    for (int u = blockIdx.x * blockDim.x + threadIdx.x; u < NT; u += stride) {
        if (u < NV4) {
            val_out[u] = val_in[u];
        } else {
            int s = u - NV4;
            stg_out[s] = stg_in[s];
        }
    }
}

// ---- layer-0 gates: g[row] = Wih0[row,:]·(input+prev_read) + Whh0[row,:]·h0 + b
__global__ void k_g0(const float* __restrict__ Wih, const float* __restrict__ Whh,
                     const float* __restrict__ bih, const float* __restrict__ bhh,
                     const float* __restrict__ inp, const float* __restrict__ prd,
                     const float* __restrict__ h0, float* __restrict__ g) {
    int wave = threadIdx.x >> 6, lane = threadIdx.x & 63;
    int row = blockIdx.x * 4 + wave;              // grid 512 -> rows 0..2047
    const float* wr = Wih + row * V_DIM;
    const float* wh = Whh + row * H_DIM;
    float p = 0.f;
    for (int c = lane; c < V_DIM; c += 64) p += wr[c] * (inp[c] + prd[c]);
    for (int k = lane; k < H_DIM; k += 64) p += wh[k] * h0[k];
    for (int off = 32; off; off >>= 1) p += __shfl_down(p, off, 64);
    if (lane == 0) g[row] = p + bih[row] + bhh[row];
}

// ---- layer-1 gates: g[row] = Wih1[row,:]·h1 + Whh1[row,:]·hprev + b
__global__ void k_g1(const float* __restrict__ Wih, const float* __restrict__ Whh,
                     const float* __restrict__ bih, const float* __restrict__ bhh,
                     const float* __restrict__ h1, const float* __restrict__ hprev,
                     float* __restrict__ g) {
    int wave = threadIdx.x >> 6, lane = threadIdx.x & 63;
    int row = blockIdx.x * 4 + wave;
    const float* wr = Wih + row * H_DIM;
    const float* wh = Whh + row * H_DIM;
    float p = 0.f;
    for (int k = lane; k < H_DIM; k += 64) p += wr[k] * h1[k] + wh[k] * hprev[k];
    for (int off = 32; off; off >>= 1) p += __shfl_down(p, off, 64);
    if (lane == 0) g[row] = p + bih[row] + bhh[row];
}

// ---- LSTM cell nonlinearity (gate order i,f,g,o per PyTorch layout)
__global__ void k_cell(const float* __restrict__ g, const float* __restrict__ cprev,
                       float* __restrict__ h, float* __restrict__ c,
                       float* __restrict__ h_out, float* __restrict__ c_out) {
    int j = threadIdx.x;  // 512
    float ig = sigmoidf(g[j]);
    float fg = sigmoidf(g[H_DIM + j]);
    float gg = tanhf(g[2 * H_DIM + j]);
    float og = sigmoidf(g[3 * H_DIM + j]);
    float cn = fg * cprev[j] + ig * gg;
    float hn = og * tanhf(cn);
    h[j] = hn; c[j] = cn;
    h_out[j] = hn;
    c_out[j] = cn;
}

// ---- heads: vt_acc[c] = sum_k h2[k]*Wv[k,c]; ot_acc[j] = sum_k h2[k]*Wo[k,j]
__global__ void k_heads(const float* __restrict__ h2, const float* __restrict__ Wv,
                        const float* __restrict__ Wo, float* __restrict__ vt_acc,
                        float* __restrict__ ot_acc) {
    int t = threadIdx.x;   // 256
    int b = blockIdx.x;    // 32 blocks, 16 k's each
    float a0 = 0.f, a1 = 0.f, av = 0.f;
    for (int kk = 0; kk < 16; ++kk) {
        int k = b * 16 + kk;
        float hv = h2[k];
        a0 += hv * Wo[k * H_DIM + t];
        a1 += hv * Wo[k * H_DIM + t + 256];
        if (t < V_DIM) av += hv * Wv[k * V_DIM + t];
    }
    atomicAdd(&ot_acc[t], a0);
    atomicAdd(&ot_acc[t + 256], a1);
    if (t < V_DIM) atomicAdd(&vt_acc[t], av);
}

// ---- finalize heads: dt/ut dots, tanh for vt/ot, write ot / Val row T / stg[T]
__global__ void k_hfin(const float* __restrict__ h2,
                       const float* __restrict__ Wd, const float* __restrict__ Bd,
                       const float* __restrict__ Wu, const float* __restrict__ Bu,
                       const float* __restrict__ Bv, const float* __restrict__ Bo,
                       const float* __restrict__ vt_acc, const float* __restrict__ ot_acc,
                       float* __restrict__ dtut, float* __restrict__ vt,
                       float* __restrict__ out) {
    __shared__ float sd[H_DIM], su[H_DIM];
    int t = threadIdx.x;  // 512
    sd[t] = h2[t] * Wd[t];
    su[t] = h2[t] * Wu[t];
    __syncthreads();
    for (int s = 256; s; s >>= 1) {
        if (t < s) { sd[t] += sd[t + s]; su[t] += su[t + s]; }
        __syncthreads();
    }
    if (t == 0) {
        float dt = sigmoidf(sd[0] + Bd[0]);
        float ut = sigmoidf(su[0] + Bu[0]);
        dtut[0] = dt; dtut[1] = ut;
        out[STG_OFF + T_DEPTH] = dt;             // stg[T] = dt
    }
    float ot = tanhf(ot_acc[t] + Bo[t]);
    out[OT_OFF + t] = ot;
    if (t < V_DIM) {
        float v = tanhf(vt_acc[t] + Bv[t]);
        vt[t] = v;
        out[VAL_OFF + T_DEPTH * V_DIM + t] = v;  // Val row T = vt
    }
}

// ---- fused top walk: exact pop-scan head rewrite + exact early-terminated rt
__global__ void k_top(const float* __restrict__ prev_stg, const float* __restrict__ prev_val,
                      const float* __restrict__ dtut, const float* __restrict__ vt,
                      float* __restrict__ out) {
    int t = threadIdx.x;  // 192
    float dt = dtut[0];
    float u  = dtut[1];   // pop carry (starts at ut)
    float r  = 1.0f;      // read carry
    float acc = 0.f;
    // i = T (freshly pushed row): stg[T]=dt (already written), coef = min(dt, max(0,r))
    {
        float coef = fminf(dt, fmaxf(0.f, r));
        if (t < V_DIM) acc += coef * vt[t];
        r -= dt;
    }
    for (int i = T_DEPTH - 1; i >= 0; --i) {
        bool pop_active = (u > 0.f);
        if (!pop_active && r <= 0.f) break;   // below: sn == s (bulk copy correct), coef == 0
        float s  = prev_stg[i];               // wave-uniform load
        float sn = fmaxf(0.f, s - fmaxf(0.f, u));
        u -= sn;
        if (pop_active && t == 0) out[STG_OFF + i] = sn;
        float coef = fminf(sn, fmaxf(0.f, r));
        r -= sn;
        if (coef > 0.f && t < V_DIM) acc += coef * prev_val[i * V_DIM + t];
    }
    if (t < V_DIM) out[RT_OFF + t] = acc;
}

extern "C" void kernel_launch(void* const* d_in, const int* in_sizes, int n_in,
                              void* d_out, int out_size, void* d_ws, size_t ws_size,
                              hipStream_t stream) {
    (void)in_sizes; (void)n_in; (void)out_size; (void)ws_size;
    const float* input     = (const float*)d_in[0];
    const float* prev_Val  = (const float*)d_in[1];
    const float* prev_stg  = (const float*)d_in[2];
    const float* prev_read = (const float*)d_in[3];
    const float* prev_h    = (const float*)d_in[4];
    const float* prev_c    = (const float*)d_in[5];
    const float* W_ih0 = (const float*)d_in[6];
    const float* W_hh0 = (const float*)d_in[7];
    const float* b_ih0 = (const float*)d_in[8];
    const float* b_hh0 = (const float*)d_in[9];
    const float* W_ih1 = (const float*)d_in[10];
    const float* W_hh1 = (const float*)d_in[11];
    const float* b_ih1 = (const float*)d_in[12];
    const float* b_hh1 = (const float*)d_in[13];
    const float* Wd = (const float*)d_in[14];
    const float* Bd = (const float*)d_in[15];
    const float* Wu = (const float*)d_in[16];
    const float* Bu = (const float*)d_in[17];
    const float* Wv = (const float*)d_in[18];
    const float* Bv = (const float*)d_in[19];
    const float* Wo = (const float*)d_in[20];
    const float* Bo = (const float*)d_in[21];

    float* out = (float*)d_out;
    float* ws  = (float*)d_ws;

    // zero the small ws accumulators (ws is poisoned 0xAA before every launch)
    hipMemsetAsync(d_ws, 0, WS_TOTAL * sizeof(float), stream);

    // big streaming copy (independent of everything; stg head fixed later by k_top)
    k_bulk<<<4096, 256, 0, stream>>>((const float4*)prev_Val, (const float2*)prev_stg, out);

    // LSTM chain
    k_g0<<<512, 256, 0, stream>>>(W_ih0, W_hh0, b_ih0, b_hh0, input, prev_read,
                                  prev_h, ws + WS_G0);
    k_cell<<<1, 512, 0, stream>>>(ws + WS_G0, prev_c, ws + WS_H1, ws + WS_C1,
                                  out + HN_OFF, out + CN_OFF);
    k_g1<<<512, 256, 0, stream>>>(W_ih1, W_hh1, b_ih1, b_hh1, ws + WS_H1,
                                  prev_h + H_DIM, ws + WS_G1);
    k_cell<<<1, 512, 0, stream>>>(ws + WS_G1, prev_c + H_DIM, ws + WS_H2, ws + WS_C2,
                                  out + HN_OFF + H_DIM, out + CN_OFF + H_DIM);

    // heads
    k_heads<<<32, 256, 0, stream>>>(ws + WS_H2, Wv, Wo, ws + WS_VTACC, ws + WS_OTACC);
    k_hfin<<<1, 512, 0, stream>>>(ws + WS_H2, Wd, Bd, Wu, Bu, Bv, Bo,
                                  ws + WS_VTACC, ws + WS_OTACC,
                                  ws + WS_DTUT, ws + WS_VT, out);

    // exact top-of-stack walk: pop head + rt
    k_top<<<1, 192, 0, stream>>>(prev_stg, prev_Val, ws + WS_DTUT, ws + WS_VT, out);
}